// Round 9
// baseline (612.022 us; speedup 1.0000x reference)
//
#include <hip/hip_runtime.h>
#include <climits>
#include <cmath>

// DetectPeaks: xcorr [16,1,256,8192] f32 -> (neighbor_score, topk_scores, topk_index), each [rows,3]
// rows = 4096, W = 8192 (2048 float4 quads per row).
// Round-9: copy-kernel-shaped two-pass structure.
//   Pass 1 (scan): 32768 blocks x 256 threads, ONE quad per thread, 4 independent waves
//     per block (no barrier, no LDS). Wave w of the row covers 64 quads = 256 elems;
//     neighbors via shfl + 2 predicated edge loads; per-quad top-2 pruning (<=2 local
//     maxima in 4 contiguous lags); 6-round shfl-tree merge; lane 0 writes the wave's
//     top-3 (val,idx) pairs to workspace. Short-lived waves => continuous load stream.
//   Pass 2 (combine): one wave per row merges the row's 32x3 = 96 candidates, gathers
//     neighbor scores, writes the 9 outputs.

#define PW    8192
#define PNLAG (PW / 2)
#define ROWS  4096
#define WPR   32              // waves per row in pass 1 (each covers 256 elems)
#define GRID1 (ROWS * WPR / 4)   // 32768 blocks of 4 waves
#define GRID2 (ROWS / 4)         // 1024 blocks of 4 waves

__device__ __forceinline__ bool better(float av, int ai, float bv, int bi) {
  return (av > bv) || ((av == bv) && (ai < bi));   // lax.top_k: ties -> lower index
}

__device__ __forceinline__ void insert3_full(float v, int i,
                                             float &v0, int &i0,
                                             float &v1, int &i1,
                                             float &v2, int &i2) {
  if (better(v, i, v2, i2)) {
    if (better(v, i, v1, i1)) {
      if (better(v, i, v0, i0)) {
        v2 = v1; i2 = i1; v1 = v0; i1 = i0; v0 = v; i0 = i;
      } else {
        v2 = v1; i2 = i1; v1 = v; i1 = i;
      }
    } else {
      v2 = v; i2 = i;
    }
  }
}

// 6-round wave-wide (64-lane) tree merge of sorted top-3 triples.
__device__ __forceinline__ void wave_merge3(float &v0, int &i0, float &v1, int &i1,
                                            float &v2, int &i2, int lane) {
#pragma unroll
  for (int off = 32; off > 0; off >>= 1) {
    float ov0 = __shfl_down(v0, off);
    int   oi0 = __shfl_down(i0, off);
    float ov1 = __shfl_down(v1, off);
    int   oi1 = __shfl_down(i1, off);
    float ov2 = __shfl_down(v2, off);
    int   oi2 = __shfl_down(i2, off);
    if (lane + off < 64) {
      insert3_full(ov0, oi0, v0, i0, v1, i1, v2, i2);
      insert3_full(ov1, oi1, v0, i0, v1, i1, v2, i2);
      insert3_full(ov2, oi2, v0, i0, v1, i1, v2, i2);
    }
  }
}

// ---------------- Pass 1: scan ----------------
__global__ __launch_bounds__(256)
void scan_kernel(const float* __restrict__ x, float2* __restrict__ pw) {
  const int t    = threadIdx.x;
  const int lane = t & 63;
  const int wv   = t >> 6;
  const int gw   = blockIdx.x * 4 + wv;    // global wave id
  const int row  = gw >> 5;                // 32 waves per row
  const int wsl  = gw & 31;                // wave slot within row
  const float* __restrict__ xr = x + (size_t)row * PW;

  const int q = wsl * 64 + lane;           // quad index within row
  const int p = q * 4;                     // element index of v.x
  const float4 v = ((const float4*)xr)[q];

  // span edges: lane 0 / lane 63 fetch one scalar (predicated; -inf at row ends)
  const float eL = (lane == 0  && wsl > 0)       ? xr[p - 1] : -INFINITY;
  const float eR = (lane == 63 && wsl < WPR - 1) ? xr[p + 4] : -INFINITY;
  const float lu = __shfl_up(v.w, 1);
  const float rd = __shfl_down(v.x, 1);
  const float left  = (lane == 0)  ? eL : lu;
  const float right = (lane == 63) ? eR : rd;

  // sliding 3-max over the 4 positions
  const float p01 = fmaxf(v.x, v.y);
  const float p12 = fmaxf(v.y, v.z);
  const float p23 = fmaxf(v.z, v.w);
  const float m0 = fmaxf(left, p01);
  const float m1 = fmaxf(p01, v.z);
  const float m2 = fmaxf(p12, v.w);
  const float m3 = fmaxf(p23, right);

  // NMS score: x where local max else 0
  const float s0 = (v.x == m0) ? v.x : 0.0f;
  const float s1 = (v.y == m1) ? v.y : 0.0f;
  const float s2 = (v.z == m2) ? v.z : 0.0f;
  const float s3 = (v.w == m3) ? v.w : 0.0f;

  // quad top-2 (left arg of >= always lower index => tie->lower-index preserved);
  // a window of 4 contiguous lags holds at most 2 local maxima.
  const bool  a01 = s0 >= s1;
  const float hiA = a01 ? s0 : s1;   const int hiAi = a01 ? p     : p + 1;
  const float loA = a01 ? s1 : s0;   const int loAi = a01 ? p + 1 : p;
  const bool  a23 = s2 >= s3;
  const float hiB = a23 ? s2 : s3;   const int hiBi = a23 ? p + 2 : p + 3;
  const float loB = a23 ? s3 : s2;   const int loBi = a23 ? p + 3 : p + 2;

  const bool  ab  = hiA >= hiB;
  float v0 = ab ? hiA : hiB;         int i0 = ab ? hiAi : hiBi;
  const bool  sb  = ab ? (loA >= hiB) : (hiA >= loB);
  float v1 = ab ? (sb ? loA : hiB) : (sb ? hiA : loB);
  int   i1 = ab ? (sb ? loAi : hiBi) : (sb ? hiAi : loBi);
  float v2 = -INFINITY;              int i2 = INT_MAX;

  wave_merge3(v0, i0, v1, i1, v2, i2, lane);

  if (lane == 0) {
    float2* c = pw + (size_t)gw * 3;
    c[0] = make_float2(v0, __int_as_float(i0));
    c[1] = make_float2(v1, __int_as_float(i1));
    c[2] = make_float2(v2, __int_as_float(i2));
  }
}

// ---------------- Pass 2: combine ----------------
__global__ __launch_bounds__(256)
void combine_kernel(const float* __restrict__ x, const float2* __restrict__ pw,
                    float* __restrict__ out) {
  const int t    = threadIdx.x;
  const int lane = t & 63;
  const int wv   = t >> 6;
  const int row  = blockIdx.x * 4 + wv;    // one wave per row
  const float* __restrict__ xr = x + (size_t)row * PW;
  const float2* __restrict__ c = pw + (size_t)row * (WPR * 3);   // 96 candidates

  float v0 = -INFINITY, v1 = -INFINITY, v2 = -INFINITY;
  int   i0 = INT_MAX,   i1 = INT_MAX,   i2 = INT_MAX;

  const float2 a = c[lane];                // lanes 0..63 cover cands 0..63
  insert3_full(a.x, __float_as_int(a.y), v0, i0, v1, i1, v2, i2);
  if (lane < WPR * 3 - 64) {               // lanes 0..31 cover cands 64..95
    const float2 b = c[64 + lane];
    insert3_full(b.x, __float_as_int(b.y), v0, i0, v1, i1, v2, i2);
  }

  wave_merge3(v0, i0, v1, i1, v2, i2, lane);

  if (lane == 0) {
    float* __restrict__ nb = out;                      // neighbor_score
    float* __restrict__ ts = out + (size_t)ROWS * 3;   // topk_scores
    float* __restrict__ ti = out + (size_t)ROWS * 6;   // topk_index (as float)
    const int top = i0;
#pragma unroll
    for (int k = 0; k < 3; ++k) {
      int idx = top - 1 + k;
      idx = idx < 0 ? 0 : (idx > PW - 1 ? PW - 1 : idx);
      nb[row * 3 + k] = xr[idx];                       // L2/L3-warm gather
    }
    ts[row * 3 + 0] = v0;
    ts[row * 3 + 1] = v1;
    ts[row * 3 + 2] = v2;
    ti[row * 3 + 0] = (float)(i0 - PNLAG);
    ti[row * 3 + 1] = (float)(i1 - PNLAG);
    ti[row * 3 + 2] = (float)(i2 - PNLAG);
  }
}

extern "C" void kernel_launch(void* const* d_in, const int* in_sizes, int n_in,
                              void* d_out, int out_size, void* d_ws, size_t ws_size,
                              hipStream_t stream) {
  const float* x = (const float*)d_in[0];
  float* out = (float*)d_out;
  float2* pw = (float2*)d_ws;              // 4096*32*3*8 B = 3.15 MB scratch
  scan_kernel<<<GRID1, 256, 0, stream>>>(x, pw);
  combine_kernel<<<GRID2, 256, 0, stream>>>(x, pw, out);
}